// Round 3
// baseline (313.229 us; speedup 1.0000x reference)
//
#include <hip/hip_runtime.h>

// Problem constants (match reference)
#define BATCH    64
#define HEIGHT   512
#define WIDTH    512
#define CHAN     3
#define PATCH    8
#define NPH      64
#define NPW      64
#define NP_TOT   4096          // NPH*NPW
#define NUM_MASK 3072          // 0.75 * NP_TOT

#define PER_IMG4 (HEIGHT * WIDTH * CHAN / 4)   // 196608 float4 per image
#define PER_ROW4 (WIDTH * CHAN / 4)            // 384 float4 per row
#define STRIP4   (PATCH * PER_ROW4)            // 3072 float4 per patch-row strip
#define TOTAL4   (BATCH * PER_IMG4)            // 12,582,912 float4 total

// Native vector type for nontemporal builtins (HIP's float4 wrapper is
// rejected by __builtin_nontemporal_*; this ext_vector compiles to the same
// global_load_dwordx4 / global_store_dwordx4 with the nt cache hint).
typedef float f32x4 __attribute__((ext_vector_type(4)));

// Single fused kernel. Grid = 64 images x 64 patch-rows = 4096 blocks.
// Each block owns one strip: 8 rows x 512 px x 3 ch = 3072 float4 = 48 KiB.
//
// Phase 1: build this strip's 64-byte patch mask in LDS by scanning the
//   image's 3072 masked indices (3 x int4 coalesced loads per thread).
//   mask_indices is 768 KB total -> L2/L3 resident, so the per-block rescan
//   is ~free (48 MB of L2 reads aggregate, ~1.4 us, overlapped).
//   Indices are a permutation prefix (distinct) -> racing byte-stores to
//   distinct LDS addresses, safe.
// Phase 2: out = in * mask. 75% of patches masked -> those lanes write
//   zeros WITHOUT reading input (exec-masked global_load_dwordx4 fetches
//   only active lanes' sectors: ~25% * 4/3 of input read from HBM).
//   A patch covers 24 contiguous floats per row (6 float4), so each aligned
//   float4 lies in exactly one patch -> one LDS byte lookup per 16 B.
//   Non-temporal hints keep the streaming 384 MB from thrashing the caches
//   that hold mask_indices.
//
// vs. the 2-kernel version: one dispatch instead of two, no global mask
// round-trip, no serial 64-block build kernel before the big grid.
// (d_ws is unused; the harness poison of it is independent of us.)
__global__ __launch_bounds__(256) void rm_fused(
        const int*  __restrict__ mask_indices,
        const f32x4* __restrict__ in,
        f32x4*       __restrict__ out) {
    const int blk = blockIdx.x;
    const int b   = blk >> 6;        // image index
    const int py  = blk & 63;        // patch-row index
    const int t   = threadIdx.x;

    __shared__ unsigned char sm[NPW];   // 64-byte patch mask for this strip

    if (t < NPW) sm[t] = (unsigned char)1;
    __syncthreads();

    // Phase 1: scatter zeros for indices belonging to patch-row py.
    const int4* __restrict__ idx4 =
        reinterpret_cast<const int4*>(mask_indices + b * NUM_MASK);
    const int lo = py << 6;
#pragma unroll
    for (int k = 0; k < 3; ++k) {
        int4 v = idx4[t + 256 * k];
        int d;
        d = v.x - lo; if ((unsigned)d < (unsigned)NPW) sm[d] = (unsigned char)0;
        d = v.y - lo; if ((unsigned)d < (unsigned)NPW) sm[d] = (unsigned char)0;
        d = v.z - lo; if ((unsigned)d < (unsigned)NPW) sm[d] = (unsigned char)0;
        d = v.w - lo; if ((unsigned)d < (unsigned)NPW) sm[d] = (unsigned char)0;
    }
    __syncthreads();

    // Phase 2: apply. Strip-local float4 index r = j*256 + t (coalesced:
    // each instruction's wave covers 1024 contiguous bytes).
    const int strip_base = b * PER_IMG4 + py * STRIP4;
#pragma unroll
    for (int j = 0; j < 12; ++j) {
        const int r  = j * 256 + t;
        const int x4 = r % PER_ROW4;     // j is compile-time -> magic-mul
        const int px = x4 / 6;           // 6 float4 per patch along x
        f32x4 v = (f32x4)(0.f, 0.f, 0.f, 0.f);
        if (sm[px]) v = __builtin_nontemporal_load(&in[strip_base + r]);
        __builtin_nontemporal_store(v, &out[strip_base + r]);
    }
}

extern "C" void kernel_launch(void* const* d_in, const int* in_sizes, int n_in,
                              void* d_out, int out_size, void* d_ws, size_t ws_size,
                              hipStream_t stream) {
    const float* images       = (const float*)d_in[0];
    const int*   mask_indices = (const int*)d_in[1];
    float*       out          = (float*)d_out;
    (void)d_ws; (void)ws_size;

    rm_fused<<<BATCH * NPH, 256, 0, stream>>>(
        mask_indices, (const f32x4*)images, (f32x4*)out);
}

// Round 4
// 305.775 us; speedup vs baseline: 1.0244x; 1.0244x over previous
//
#include <hip/hip_runtime.h>

// Problem constants (match reference)
#define BATCH    64
#define HEIGHT   512
#define WIDTH    512
#define CHAN     3
#define PATCH    8
#define NPH      64
#define NPW      64
#define NP_TOT   4096          // NPH*NPW
#define NUM_MASK 3072          // 0.75 * NP_TOT

#define PER_IMG4 (HEIGHT * WIDTH * CHAN / 4)   // 196608 float4 per image
#define PER_ROW4 (WIDTH * CHAN / 4)            // 384 float4 per row
#define TOTAL4   (BATCH * PER_IMG4)            // 12,582,912 float4 total
#define VPT      4                             // float4 per thread (MLP depth)
#define TILE4    (256 * VPT)                   // 1024 float4 per block

// Native vector type for nontemporal builtins (HIP's float4 wrapper is
// rejected by __builtin_nontemporal_*; same global_load/store_dwordx4 + nt).
typedef float f32x4 __attribute__((ext_vector_type(4)));

// Kernel 1 (merged init+scatter): one block per image.
//  - 256 threads vector-init the image's 4096-byte mask region to 1
//  - __syncthreads()
//  - each thread scatters 12 zero bytes at the image's masked patch indices.
// Indices within an image are a permutation prefix (distinct) -> race-free.
// (d_ws is re-poisoned before every launch, so init must run each call.)
__global__ __launch_bounds__(256) void rm_build_mask(
        const int* __restrict__ mask_indices,
        unsigned char* __restrict__ mask) {
    const int b = blockIdx.x;
    const int t = threadIdx.x;

    uint4 ones = make_uint4(0x01010101u, 0x01010101u, 0x01010101u, 0x01010101u);
    reinterpret_cast<uint4*>(mask + b * NP_TOT)[t] = ones;
    __syncthreads();

    const int* __restrict__ idx = mask_indices + b * NUM_MASK;
    unsigned char* __restrict__ m = mask + b * NP_TOT;
#pragma unroll
    for (int j = 0; j < 12; ++j) {
        m[idx[t + j * 256]] = (unsigned char)0;
    }
}

// Kernel 2: out = in * mask, VPT=4 float4 per thread, batched for MLP:
//   loop A: 4 mask-byte lookups
//   loop B: 4 independent exec-masked nt loads (in flight simultaneously)
//   loop C: 4 nt stores
// 75% of patches masked -> those lanes write zeros WITHOUT reading input
// (exec-masked global_load_dwordx4 fetches only active lanes' sectors:
// each 96 B unmasked patch row-segment touches exactly two 64 B sectors,
// so reads ~ 25% * 4/3 of the input ~ 67 MB). A patch covers 24 contiguous
// floats per row (6 float4), so each aligned float4 lies in exactly one
// patch -> one byte-mask lookup per 16 B (L1-broadcast across the wave).
// Non-temporal hints keep the 384 MB stream from thrashing the caches
// holding the 256 KB mask.
__global__ __launch_bounds__(256) void rm_apply_mask(
        const f32x4* __restrict__ in,
        f32x4*       __restrict__ out,
        const unsigned char* __restrict__ mask) {
    const int base = blockIdx.x * TILE4 + threadIdx.x;

    unsigned char m[VPT];
#pragma unroll
    for (int j = 0; j < VPT; ++j) {
        const int tid = base + j * 256;
        const int b   = tid / PER_IMG4;
        const int r   = tid - b * PER_IMG4;
        const int y   = r / PER_ROW4;
        const int x4  = r - y * PER_ROW4;
        const int px  = x4 / 6;          // 6 float4 per patch along x
        const int py  = y >> 3;          // 8 rows per patch
        m[j] = mask[b * NP_TOT + (py << 6) + px];
    }

    f32x4 v[VPT];
#pragma unroll
    for (int j = 0; j < VPT; ++j) {
        v[j] = (f32x4)(0.f, 0.f, 0.f, 0.f);
        if (m[j]) v[j] = __builtin_nontemporal_load(&in[base + j * 256]);
    }

#pragma unroll
    for (int j = 0; j < VPT; ++j) {
        __builtin_nontemporal_store(v[j], &out[base + j * 256]);
    }
}

extern "C" void kernel_launch(void* const* d_in, const int* in_sizes, int n_in,
                              void* d_out, int out_size, void* d_ws, size_t ws_size,
                              hipStream_t stream) {
    const float* images       = (const float*)d_in[0];
    const int*   mask_indices = (const int*)d_in[1];
    float*       out          = (float*)d_out;
    unsigned char* mask       = (unsigned char*)d_ws;   // 256 KB used

    // 1) mask := 1 then mask[b, idx] := 0   (one block per image)
    rm_build_mask<<<BATCH, 256, 0, stream>>>(mask_indices, mask);

    // 2) out = in * mask   (TOTAL4 = 12288 * TILE4 exactly)
    rm_apply_mask<<<TOTAL4 / TILE4, 256, 0, stream>>>(
        (const f32x4*)images, (f32x4*)out, mask);
}